// Round 7
// baseline (257.757 us; speedup 1.0000x reference)
//
#include <hip/hip_runtime.h>
#include <math.h>

#define DIMX 128
#define HIDX 256
#define NBX 2048
#define NTOTX 32768
#define NMAXX 32
#define VMID 192
#define SMID 128
#define DMID 192

#define EROWS 64
#define SP 65         // odd pitch: bank=(col+r)%32 -> GEMM reads conflict-free, staging 4-way
#define NSEGMAX 128   // segment-size cap (multinomial mean 16, P(n>60) ~ 1e-16)

__device__ __forceinline__ float mishf(float v) {
    // exact identity: tanh(log1p(e^v)) = (u^2+2u)/(u^2+2u+2), u=e^v
    if (v > 20.0f) return v;          // tanh(softplus(v)) == 1.0f in fp32
    float u = expf(v);
    float t = u * (u + 2.0f);
    return v * (t / (t + 2.0f));
}

// fused encoder + mag: lane=row, wave=column-slice; weights via scalar loads
// with explicit distance-2 register double-buffer prefetch.
__global__ __launch_bounds__(512, 4) void k_enc(const float* __restrict__ x,
    const float* __restrict__ rw, const float* __restrict__ rb,
    const float* __restrict__ w1, const float* __restrict__ b1,
    const float* __restrict__ g1, const float* __restrict__ be1,
    const float* __restrict__ w2, const float* __restrict__ b2,
    float* __restrict__ h, float* __restrict__ mag) {
    __shared__ __align__(16) float sbuf[HIDX * SP];  // xT/actT/hT, reused
    __shared__ float red[512];
    __shared__ float red2[512];
    int tid = threadIdx.x;
    int r = tid & 63;       // row lane
    int tg = tid >> 6;      // wave id = column group
    int rowbase = blockIdx.x * EROWS;

    // stage x^T: coalesced float4 reads, 4-way-conflict b32 writes
#pragma unroll
    for (int it = 0; it < 4; it++) {
        int f4 = it * 512 + tid;
        int rr = f4 >> 5, kq = f4 & 31;
        float4 v = ((const float4*)x)[(size_t)(rowbase + rr) * 32 + kq];
        sbuf[(4 * kq + 0) * SP + rr] = v.x;
        sbuf[(4 * kq + 1) * SP + rr] = v.y;
        sbuf[(4 * kq + 2) * SP + rr] = v.z;
        sbuf[(4 * kq + 3) * SP + rr] = v.w;
    }
    __syncthreads();

    // mag = x . rank_w (wave 0 only; xT read-only here)
    if (tid < 64) {
        float s = 0.0f;
        for (int k = 0; k < DIMX; k++) s += sbuf[k * SP + tid] * rw[k];
        mag[rowbase + tid] = s + rb[0];
    }

    // ---- GEMM1: 24 cols/thread; dist-2 scalar prefetch ----
    int cb1 = __builtin_amdgcn_readfirstlane(tg * 24);
    const float* w1p = w1 + cb1;
    float acc[24];
#pragma unroll
    for (int j = 0; j < 24; j++) acc[j] = 0.0f;
    float wA[24], wB[24];
#pragma unroll
    for (int j = 0; j < 24; j++) wA[j] = w1p[j];
#pragma unroll
    for (int j = 0; j < 24; j++) wB[j] = w1p[VMID + j];
    for (int k = 0; k < DIMX; k += 2) {
        float x0 = sbuf[k * SP + r];
        float x1 = sbuf[(k + 1) * SP + r];
        int k2 = (k + 2 < DIMX) ? (k + 2) : k;   // uniform clamp (tail reload, unused)
        int k3 = (k + 3 < DIMX) ? (k + 3) : k;
#pragma unroll
        for (int j = 0; j < 24; j++) acc[j] += wA[j] * x0;
#pragma unroll
        for (int j = 0; j < 24; j++) wA[j] = w1p[k2 * VMID + j];
#pragma unroll
        for (int j = 0; j < 24; j++) acc[j] += wB[j] * x1;
#pragma unroll
        for (int j = 0; j < 24; j++) wB[j] = w1p[k3 * VMID + j];
    }

    // ---- LayerNorm across the 8 column groups (LDS reduce) ----
    float part = 0.0f;
#pragma unroll
    for (int j = 0; j < 24; j++) { acc[j] += b1[cb1 + j]; part += acc[j]; }
    red[tg * 64 + r] = part;
    __syncthreads();
    float mean = 0.0f;
#pragma unroll
    for (int q = 0; q < 8; q++) mean += red[q * 64 + r];
    mean *= (1.0f / 192.0f);
    float vpart = 0.0f;
#pragma unroll
    for (int j = 0; j < 24; j++) { acc[j] -= mean; vpart += acc[j] * acc[j]; }
    red2[tg * 64 + r] = vpart;
    __syncthreads();
    float var = 0.0f;
#pragma unroll
    for (int q = 0; q < 8; q++) var += red2[q * 64 + r];
    var *= (1.0f / 192.0f);
    float inv = 1.0f / sqrtf(var + 1e-5f);
#pragma unroll
    for (int j = 0; j < 24; j++)
        acc[j] = mishf(acc[j] * inv * g1[cb1 + j] + be1[cb1 + j]);
    // write act^T (xT dead: all reads done before the two barriers above)
#pragma unroll
    for (int j = 0; j < 24; j++) sbuf[(cb1 + j) * SP + r] = acc[j];
    __syncthreads();

    // ---- GEMM2: 32 cols/thread; dist-2 scalar prefetch ----
    int cb2 = __builtin_amdgcn_readfirstlane(tg * 32);
    const float* w2p = w2 + cb2;
    float acc2[32];
#pragma unroll
    for (int j = 0; j < 32; j++) acc2[j] = 0.0f;
    float vA[32], vB[32];
#pragma unroll
    for (int j = 0; j < 32; j++) vA[j] = w2p[j];
#pragma unroll
    for (int j = 0; j < 32; j++) vB[j] = w2p[HIDX + j];
    for (int k = 0; k < VMID; k += 2) {
        float a0 = sbuf[k * SP + r];
        float a1 = sbuf[(k + 1) * SP + r];
        int k2 = (k + 2 < VMID) ? (k + 2) : k;
        int k3 = (k + 3 < VMID) ? (k + 3) : k;
#pragma unroll
        for (int j = 0; j < 32; j++) acc2[j] += vA[j] * a0;
#pragma unroll
        for (int j = 0; j < 32; j++) vA[j] = w2p[k2 * HIDX + j];
#pragma unroll
        for (int j = 0; j < 32; j++) acc2[j] += vB[j] * a1;
#pragma unroll
        for (int j = 0; j < 32; j++) vB[j] = w2p[k3 * HIDX + j];
    }
#pragma unroll
    for (int j = 0; j < 32; j++) acc2[j] += b2[cb2 + j];
    __syncthreads();      // all GEMM2 LDS reads done
#pragma unroll
    for (int j = 0; j < 32; j++) sbuf[(cb2 + j) * SP + r] = acc2[j];
    __syncthreads();

    // coalesced h store via LDS transpose
#pragma unroll
    for (int it = 0; it < 8; it++) {
        int f4 = it * 512 + tid;
        int rr = f4 >> 6, cq = f4 & 63;
        float4 v;
        v.x = sbuf[(4 * cq + 0) * SP + rr];
        v.y = sbuf[(4 * cq + 1) * SP + rr];
        v.z = sbuf[(4 * cq + 2) * SP + rr];
        v.w = sbuf[(4 * cq + 3) * SP + rr];
        ((float4*)h)[(size_t)(rowbase + rr) * 64 + cq] = v;
    }
}

// seg-bounds + in-LDS rank + z segment sum (inline sincos); writes zre/zim
__global__ __launch_bounds__(256) void k_z(const float* __restrict__ h,
    const int* __restrict__ batch, const float* __restrict__ mag,
    const float* __restrict__ cw, const float* __restrict__ cb,
    float* __restrict__ zre, float* __restrict__ zim) {
    __shared__ float magL[NSEGMAX];
    __shared__ int   ordL[NSEGMAX];
    __shared__ int   shs, shn;
    int b = blockIdx.x, j = threadIdx.x;
    if (j == 0) {
        int lo = 0, hi = NTOTX;
        while (lo < hi) { int m = (lo + hi) >> 1; if (batch[m] < b) lo = m + 1; else hi = m; }
        int stt = lo;
        hi = NTOTX;
        while (lo < hi) { int m = (lo + hi) >> 1; if (batch[m] <= b) lo = m + 1; else hi = m; }
        shs = stt; shn = lo - stt;
    }
    __syncthreads();
    int s = shs, n_true = shn;
    int n = (n_true < NSEGMAX) ? n_true : NSEGMAX;
    if (j < n) magL[j] = mag[s + j];
    __syncthreads();
    if (j < n) {                          // stable rank within segment (lexsort tie: idx)
        float mi = magL[j];
        int rk = 0;
        for (int q = 0; q < n; q++) {
            float mq = magL[q];
            rk += (mq < mi) || (mq == mi && q < j);
        }
        ordL[rk] = s + j;
    }
    __syncthreads();

    float t = (float)j * (1.0f / 255.0f);
    float zr = 0.f, zi = 0.f;
    int p = 0;
    for (; p + 1 < n; p += 2) {           // accumulation ORDER = p ascending (fp32-exact)
        int e0 = ordL[p], e1 = ordL[p + 1];
        float hv0 = h[(size_t)e0 * HIDX + j];
        float hv1 = h[(size_t)e1 * HIDX + j];
        float sv0, cv0, sv1, cv1;
        sincosf((t * (float)p) * 8.0f, &sv0, &cv0);
        sincosf((t * (float)(p + 1)) * 8.0f, &sv1, &cv1);
        zr += hv0 * cv0; zi += hv0 * sv0;
        zr += hv1 * cv1; zi += hv1 * sv1;
    }
    if (p < n) {
        int e = ordL[p];
        float hv = h[(size_t)e * HIDX + j];
        float sv, cv;
        sincosf((t * (float)p) * 8.0f, &sv, &cv);
        zr += hv * cv; zi += hv * sv;
    }
    float nf = (float)n_true;
    zre[(size_t)b * HIDX + j] = zr + nf * cw[j] + cb[j];
    zim[(size_t)b * HIDX + j] = zi;
}

// size MLP, 8 batches/block: sw1 stream amortized 8x. Reduction order == R6.
__global__ __launch_bounds__(256) void k_size(const float* __restrict__ zre,
    const float* __restrict__ cw, const float* __restrict__ cb,
    const float* __restrict__ sw1, const float* __restrict__ sb1,
    const float* __restrict__ sg, const float* __restrict__ sbe,
    const float* __restrict__ sw2, const float* __restrict__ sb2,
    float* __restrict__ zcre, float* __restrict__ out_mask,
    float* __restrict__ out_np, int* __restrict__ npredi) {
    __shared__ float zs[8][HIDX];          // 8 KB
    __shared__ float rA[16], rB[16], rC[16];
    __shared__ float snpf[8];
    int tid = threadIdx.x;
    int b0 = blockIdx.x * 8;
#pragma unroll
    for (int it = 0; it < 8; it++) {
        int idx = it * 256 + tid;
        zs[idx >> 8][idx & 255] = zre[(size_t)(b0 + (idx >> 8)) * HIDX + (idx & 255)];
    }
    __syncthreads();

    int g = tid >> 7;          // batch-half: batches b0+4g .. b0+4g+3
    int j = tid & 127;
    int wv = (tid >> 6) & 1;   // wave within group
    float acc[4];
    float vb1 = sb1[j];
#pragma unroll
    for (int q = 0; q < 4; q++) acc[q] = vb1;
    for (int k = 0; k < HIDX; k++) {
        float w = sw1[k * SMID + j];
#pragma unroll
        for (int q = 0; q < 4; q++) acc[q] += zs[g * 4 + q][k] * w;
    }
    // mean: per-wave shfl reduce then 2-wave combine (same order as before)
#pragma unroll
    for (int q = 0; q < 4; q++) {
        float sa = acc[q];
#pragma unroll
        for (int off = 32; off; off >>= 1) sa += __shfl_xor(sa, off, 64);
        if ((tid & 63) == 0) rA[(g * 2 + wv) * 4 + q] = sa;
    }
    __syncthreads();
    float d[4];
#pragma unroll
    for (int q = 0; q < 4; q++) {
        float mean = (rA[(g * 2) * 4 + q] + rA[(g * 2 + 1) * 4 + q]) / 128.0f;
        d[q] = acc[q] - mean;
        float qq = d[q] * d[q];
#pragma unroll
        for (int off = 32; off; off >>= 1) qq += __shfl_xor(qq, off, 64);
        if ((tid & 63) == 0) rB[(g * 2 + wv) * 4 + q] = qq;
    }
    __syncthreads();
    float gj = sg[j], bej = sbe[j], w2j = sw2[j];
#pragma unroll
    for (int q = 0; q < 4; q++) {
        float var = (rB[(g * 2) * 4 + q] + rB[(g * 2 + 1) * 4 + q]) / 128.0f;
        float lv = d[q] * (1.0f / sqrtf(var + 1e-5f)) * gj + bej;
        float p2 = mishf(lv) * w2j;
#pragma unroll
        for (int off = 32; off; off >>= 1) p2 += __shfl_xor(p2, off, 64);
        if ((tid & 63) == 0) rC[(g * 2 + wv) * 4 + q] = p2;
    }
    __syncthreads();
    if (tid < 8) {
        int q = tid & 3, gg = tid >> 2;
        float h2 = rC[(gg * 2) * 4 + q] + rC[(gg * 2 + 1) * 4 + q] + sb2[0];
        float npf = fmaxf(rintf(h2), 0.0f);   // rintf == round-half-even == jnp.round
        int npi = min((int)npf, NMAXX);
        snpf[tid] = npf;
        out_np[b0 + tid] = (float)npi;
        npredi[b0 + tid] = npi;
    }
    __syncthreads();
    // zc = z - (npf*cw + cb), 8 batches x 256 cols
#pragma unroll
    for (int it = 0; it < 8; it++) {
        int idx = it * 256 + tid;
        int bi = idx >> 8, jj = idx & 255;
        zcre[(size_t)(b0 + bi) * HIDX + jj] = zs[bi][jj] - (snpf[bi] * cw[jj] + cb[jj]);
    }
    {   // mask: 8 batches x 32
        int bi = tid >> 5, m = tid & 31;
        out_mask[(b0 + bi) * NMAXX + m] = (m < ((int)fminf(snpf[bi], 32.0f))) ? 1.0f : 0.0f;
    }
}

// decoder: per-(m,b) blocks; masked rows write zeros; inline sincos keys
__global__ __launch_bounds__(256) void k_dec(const float* __restrict__ zcre,
    const float* __restrict__ zim, const int* __restrict__ npredi,
    const float* __restrict__ w1, const float* __restrict__ b1,
    const float* __restrict__ w2, const float* __restrict__ b2,
    float* __restrict__ xr) {
    int m = blockIdx.x, b = blockIdx.y;
    int tid = threadIdx.x;
    size_t row = (size_t)b * NMAXX + m;
    if (m >= npredi[b]) {
        if (tid < DIMX) xr[row * DIMX + tid] = 0.0f;
        return;
    }
    __shared__ float zp[HIDX];
    __shared__ float a[DMID];
    {
        float t = (float)tid * (1.0f / 255.0f);
        float sv, cv;
        sincosf((t * (float)m) * 8.0f, &sv, &cv);
        zp[tid] = zcre[(size_t)b * HIDX + tid] * cv - zim[(size_t)b * HIDX + tid] * sv;
    }
    __syncthreads();
    if (tid < DMID) {
        float v = b1[tid];
#pragma unroll 4
        for (int k = 0; k < HIDX; k++) v += zp[k] * w1[k * DMID + tid];
        a[tid] = mishf(v);
    }
    __syncthreads();
    if (tid < DIMX) {
        float v = b2[tid];
#pragma unroll 4
        for (int k = 0; k < DMID; k++) v += a[k] * w2[k * DIMX + tid];
        xr[row * DIMX + tid] = v;
    }
}

extern "C" void kernel_launch(void* const* d_in, const int* in_sizes, int n_in,
                              void* d_out, int out_size, void* d_ws, size_t ws_size,
                              hipStream_t stream) {
    const float* x      = (const float*)d_in[0];
    const int*   batch  = (const int*)d_in[1];
    const float* rank_w = (const float*)d_in[2];
    const float* rank_b = (const float*)d_in[3];
    const float* vw1    = (const float*)d_in[4];
    const float* vb1    = (const float*)d_in[5];
    const float* vlg    = (const float*)d_in[6];
    const float* vlb    = (const float*)d_in[7];
    const float* vw2    = (const float*)d_in[8];
    const float* vb2    = (const float*)d_in[9];
    const float* cw     = (const float*)d_in[10];
    const float* cb     = (const float*)d_in[11];
    const float* sw1    = (const float*)d_in[12];
    const float* sb1    = (const float*)d_in[13];
    const float* slg    = (const float*)d_in[14];
    const float* slb    = (const float*)d_in[15];
    const float* sw2    = (const float*)d_in[16];
    const float* sb2    = (const float*)d_in[17];
    const float* dw1    = (const float*)d_in[18];
    const float* db1    = (const float*)d_in[19];
    const float* dw2    = (const float*)d_in[20];
    const float* db2    = (const float*)d_in[21];

    char* ws = (char*)d_ws;
    size_t off = 0;
    auto alloc = [&](size_t bytes) {
        void* p = ws + off;
        off += (bytes + 255) & ~(size_t)255;
        return p;
    };
    float* mag  = (float*)alloc((size_t)NTOTX * 4);
    float* zre  = (float*)alloc((size_t)NBX * HIDX * 4);
    float* zim  = (float*)alloc((size_t)NBX * HIDX * 4);
    float* zcre = (float*)alloc((size_t)NBX * HIDX * 4);
    int*   npi  = (int*)alloc((size_t)NBX * 4);
    float* h    = (float*)alloc((size_t)NTOTX * HIDX * 4);

    float* out_xr   = (float*)d_out;
    float* out_mask = out_xr + (size_t)NBX * NMAXX * DIMX;
    float* out_np   = out_mask + (size_t)NBX * NMAXX;

    hipLaunchKernelGGL(k_enc,  dim3(NTOTX / EROWS), dim3(512), 0, stream,
                       x, rank_w, rank_b, vw1, vb1, vlg, vlb, vw2, vb2, h, mag);
    hipLaunchKernelGGL(k_z,    dim3(NBX), dim3(HIDX), 0, stream,
                       h, batch, mag, cw, cb, zre, zim);
    hipLaunchKernelGGL(k_size, dim3(NBX / 8), dim3(256), 0, stream,
                       zre, cw, cb, sw1, sb1, slg, slb, sw2, sb2,
                       zcre, out_mask, out_np, npi);
    hipLaunchKernelGGL(k_dec,  dim3(NMAXX, NBX), dim3(256), 0, stream,
                       zcre, zim, npi, dw1, db1, dw2, db2, out_xr);
    (void)in_sizes; (void)n_in; (void)out_size; (void)ws_size;
}

// Round 8
// 149.612 us; speedup vs baseline: 1.7228x; 1.7228x over previous
//
#include <hip/hip_runtime.h>
#include <math.h>

#define DIMX 128
#define HIDX 256
#define NBX 2048
#define NTOTX 32768
#define NMAXX 32
#define VMID 192
#define SMID 128
#define DMID 192

#define EROWS 64
#define SP 65         // odd pitch: GEMM reads conflict-free, staging writes 4-way
#define NSEGMAX 128   // segment-size cap (multinomial mean 16, P(n>60) ~ 1e-16)

__device__ __forceinline__ float mishf(float v) {
    // exact identity: tanh(log1p(e^v)) = (u^2+2u)/(u^2+2u+2), u=e^v
    if (v > 20.0f) return v;          // tanh(softplus(v)) == 1.0f in fp32
    float u = expf(v);
    float t = u * (u + 2.0f);
    return v * (t / (t + 2.0f));
}

// fused encoder + mag: lane=row (64 rows), 16 waves = 16 column groups.
// Weight slices wave-uniform -> scalar s_load; compiler schedules (no manual
// prefetch: SMEM+LDS share lgkmcnt, hand pipelines force full drains - R7 lesson).
// Direct h stores (64B/thread contiguous), no LDS transpose.
__global__ __launch_bounds__(1024, 2) void k_enc(const float* __restrict__ x,
    const float* __restrict__ rw, const float* __restrict__ rb,
    const float* __restrict__ w1, const float* __restrict__ b1,
    const float* __restrict__ g1, const float* __restrict__ be1,
    const float* __restrict__ w2, const float* __restrict__ b2,
    float* __restrict__ h, float* __restrict__ mag) {
    __shared__ __align__(16) float sbuf[VMID * SP];  // xT[128][65] then actT[192][65]
    __shared__ float red[1024];
    __shared__ float red2[1024];
    int tid = threadIdx.x;
    int r = tid & 63;       // row lane
    int tg = tid >> 6;      // wave id = column group (0..15)
    int rowbase = blockIdx.x * EROWS;

    // stage x^T: coalesced float4 reads
#pragma unroll
    for (int it = 0; it < 2; it++) {
        int f4 = it * 1024 + tid;
        int rr = f4 >> 5, kq = f4 & 31;
        float4 v = ((const float4*)x)[(size_t)(rowbase + rr) * 32 + kq];
        sbuf[(4 * kq + 0) * SP + rr] = v.x;
        sbuf[(4 * kq + 1) * SP + rr] = v.y;
        sbuf[(4 * kq + 2) * SP + rr] = v.z;
        sbuf[(4 * kq + 3) * SP + rr] = v.w;
    }
    __syncthreads();

    // mag = x . rank_w (wave 0 only; xT read-only here)
    if (tid < 64) {
        float s = 0.0f;
        for (int k = 0; k < DIMX; k++) s += sbuf[k * SP + tid] * rw[k];
        mag[rowbase + tid] = s + rb[0];
    }

    // ---- GEMM1: 12 cols/thread, weights scalar-loaded ----
    int cb1 = __builtin_amdgcn_readfirstlane(tg * 12);
    float acc[12];
#pragma unroll
    for (int j = 0; j < 12; j++) acc[j] = 0.0f;
#pragma unroll 4
    for (int k = 0; k < DIMX; k++) {
        float xv = sbuf[k * SP + r];
        const float* wr = w1 + k * VMID + cb1;
#pragma unroll
        for (int j = 0; j < 12; j++) acc[j] += wr[j] * xv;
    }

    // ---- LayerNorm across the 16 column groups (LDS reduce) ----
    float part = 0.0f;
#pragma unroll
    for (int j = 0; j < 12; j++) { acc[j] += b1[cb1 + j]; part += acc[j]; }
    red[tg * 64 + r] = part;
    __syncthreads();
    float mean = 0.0f;
#pragma unroll
    for (int q = 0; q < 16; q++) mean += red[q * 64 + r];
    mean *= (1.0f / 192.0f);
    float vpart = 0.0f;
#pragma unroll
    for (int j = 0; j < 12; j++) { acc[j] -= mean; vpart += acc[j] * acc[j]; }
    red2[tg * 64 + r] = vpart;
    __syncthreads();
    float var = 0.0f;
#pragma unroll
    for (int q = 0; q < 16; q++) var += red2[q * 64 + r];
    var *= (1.0f / 192.0f);
    float inv = 1.0f / sqrtf(var + 1e-5f);
#pragma unroll
    for (int j = 0; j < 12; j++)
        acc[j] = mishf(acc[j] * inv * g1[cb1 + j] + be1[cb1 + j]);
    __syncthreads();   // all GEMM1 xT reads done before actT overwrite
#pragma unroll
    for (int j = 0; j < 12; j++) sbuf[(cb1 + j) * SP + r] = acc[j];
    __syncthreads();

    // ---- GEMM2: 16 cols/thread (64B-aligned slice -> s_load_dwordx16) ----
    int cb2 = __builtin_amdgcn_readfirstlane(tg * 16);
    float acc2[16];
#pragma unroll
    for (int j = 0; j < 16; j++) acc2[j] = 0.0f;
#pragma unroll 4
    for (int k = 0; k < VMID; k++) {
        float av = sbuf[k * SP + r];
        const float* wr = w2 + k * HIDX + cb2;
#pragma unroll
        for (int j = 0; j < 16; j++) acc2[j] += wr[j] * av;
    }
    // direct h store: 64 contiguous bytes per thread
    float* hp = h + (size_t)(rowbase + r) * HIDX + cb2;
#pragma unroll
    for (int q = 0; q < 4; q++) {
        float4 v;
        v.x = acc2[4 * q + 0] + b2[cb2 + 4 * q + 0];
        v.y = acc2[4 * q + 1] + b2[cb2 + 4 * q + 1];
        v.z = acc2[4 * q + 2] + b2[cb2 + 4 * q + 2];
        v.w = acc2[4 * q + 3] + b2[cb2 + 4 * q + 3];
        ((float4*)hp)[q] = v;
    }
}

// seg-bounds + in-LDS rank + z segment sum (inline sincos); writes zre/zim
__global__ __launch_bounds__(256) void k_z(const float* __restrict__ h,
    const int* __restrict__ batch, const float* __restrict__ mag,
    const float* __restrict__ cw, const float* __restrict__ cb,
    float* __restrict__ zre, float* __restrict__ zim) {
    __shared__ float magL[NSEGMAX];
    __shared__ int   ordL[NSEGMAX];
    __shared__ int   shs, shn;
    int b = blockIdx.x, j = threadIdx.x;
    if (j == 0) {
        int lo = 0, hi = NTOTX;
        while (lo < hi) { int m = (lo + hi) >> 1; if (batch[m] < b) lo = m + 1; else hi = m; }
        int stt = lo;
        hi = NTOTX;
        while (lo < hi) { int m = (lo + hi) >> 1; if (batch[m] <= b) lo = m + 1; else hi = m; }
        shs = stt; shn = lo - stt;
    }
    __syncthreads();
    int s = shs, n_true = shn;
    int n = (n_true < NSEGMAX) ? n_true : NSEGMAX;
    if (j < n) magL[j] = mag[s + j];
    __syncthreads();
    if (j < n) {                          // stable rank within segment (lexsort tie: idx)
        float mi = magL[j];
        int rk = 0;
        for (int q = 0; q < n; q++) {
            float mq = magL[q];
            rk += (mq < mi) || (mq == mi && q < j);
        }
        ordL[rk] = s + j;
    }
    __syncthreads();

    float t = (float)j * (1.0f / 255.0f);
    float zr = 0.f, zi = 0.f;
    int p = 0;
    for (; p + 1 < n; p += 2) {           // accumulation ORDER = p ascending (fp32-exact)
        int e0 = ordL[p], e1 = ordL[p + 1];
        float hv0 = h[(size_t)e0 * HIDX + j];
        float hv1 = h[(size_t)e1 * HIDX + j];
        float sv0, cv0, sv1, cv1;
        sincosf((t * (float)p) * 8.0f, &sv0, &cv0);
        sincosf((t * (float)(p + 1)) * 8.0f, &sv1, &cv1);
        zr += hv0 * cv0; zi += hv0 * sv0;
        zr += hv1 * cv1; zi += hv1 * sv1;
    }
    if (p < n) {
        int e = ordL[p];
        float hv = h[(size_t)e * HIDX + j];
        float sv, cv;
        sincosf((t * (float)p) * 8.0f, &sv, &cv);
        zr += hv * cv; zi += hv * sv;
    }
    float nf = (float)n_true;
    zre[(size_t)b * HIDX + j] = zr + nf * cw[j] + cb[j];
    zim[(size_t)b * HIDX + j] = zi;
}

// size MLP, 8 batches/block: sw1 stream amortized 8x.
__global__ __launch_bounds__(256) void k_size(const float* __restrict__ zre,
    const float* __restrict__ cw, const float* __restrict__ cb,
    const float* __restrict__ sw1, const float* __restrict__ sb1,
    const float* __restrict__ sg, const float* __restrict__ sbe,
    const float* __restrict__ sw2, const float* __restrict__ sb2,
    float* __restrict__ zcre, float* __restrict__ out_mask,
    float* __restrict__ out_np, int* __restrict__ npredi) {
    __shared__ float zs[8][HIDX];          // 8 KB
    __shared__ float rA[16], rB[16], rC[16];
    __shared__ float snpf[8];
    int tid = threadIdx.x;
    int b0 = blockIdx.x * 8;
#pragma unroll
    for (int it = 0; it < 8; it++) {
        int idx = it * 256 + tid;
        zs[idx >> 8][idx & 255] = zre[(size_t)(b0 + (idx >> 8)) * HIDX + (idx & 255)];
    }
    __syncthreads();

    int g = tid >> 7;          // batch-half: batches b0+4g .. b0+4g+3
    int j = tid & 127;
    int wv = (tid >> 6) & 1;   // wave within group
    float acc[4];
    float vb1 = sb1[j];
#pragma unroll
    for (int q = 0; q < 4; q++) acc[q] = vb1;
    for (int k = 0; k < HIDX; k++) {
        float w = sw1[k * SMID + j];
#pragma unroll
        for (int q = 0; q < 4; q++) acc[q] += zs[g * 4 + q][k] * w;
    }
#pragma unroll
    for (int q = 0; q < 4; q++) {
        float sa = acc[q];
#pragma unroll
        for (int off = 32; off; off >>= 1) sa += __shfl_xor(sa, off, 64);
        if ((tid & 63) == 0) rA[(g * 2 + wv) * 4 + q] = sa;
    }
    __syncthreads();
    float d[4];
#pragma unroll
    for (int q = 0; q < 4; q++) {
        float mean = (rA[(g * 2) * 4 + q] + rA[(g * 2 + 1) * 4 + q]) / 128.0f;
        d[q] = acc[q] - mean;
        float qq = d[q] * d[q];
#pragma unroll
        for (int off = 32; off; off >>= 1) qq += __shfl_xor(qq, off, 64);
        if ((tid & 63) == 0) rB[(g * 2 + wv) * 4 + q] = qq;
    }
    __syncthreads();
    float gj = sg[j], bej = sbe[j], w2j = sw2[j];
#pragma unroll
    for (int q = 0; q < 4; q++) {
        float var = (rB[(g * 2) * 4 + q] + rB[(g * 2 + 1) * 4 + q]) / 128.0f;
        float lv = d[q] * (1.0f / sqrtf(var + 1e-5f)) * gj + bej;
        float p2 = mishf(lv) * w2j;
#pragma unroll
        for (int off = 32; off; off >>= 1) p2 += __shfl_xor(p2, off, 64);
        if ((tid & 63) == 0) rC[(g * 2 + wv) * 4 + q] = p2;
    }
    __syncthreads();
    if (tid < 8) {
        int q = tid & 3, gg = tid >> 2;
        float h2 = rC[(gg * 2) * 4 + q] + rC[(gg * 2 + 1) * 4 + q] + sb2[0];
        float npf = fmaxf(rintf(h2), 0.0f);   // rintf == round-half-even == jnp.round
        int npi = min((int)npf, NMAXX);
        snpf[tid] = npf;
        out_np[b0 + tid] = (float)npi;
        npredi[b0 + tid] = npi;
    }
    __syncthreads();
#pragma unroll
    for (int it = 0; it < 8; it++) {
        int idx = it * 256 + tid;
        int bi = idx >> 8, jj = idx & 255;
        zcre[(size_t)(b0 + bi) * HIDX + jj] = zs[bi][jj] - (snpf[bi] * cw[jj] + cb[jj]);
    }
    {   // mask: 8 batches x 32
        int bi = tid >> 5, m = tid & 31;
        out_mask[(b0 + bi) * NMAXX + m] = (m < ((int)fminf(snpf[bi], 32.0f))) ? 1.0f : 0.0f;
    }
}

// decoder: per-(m,b) blocks; masked rows write zeros; inline sincos keys
__global__ __launch_bounds__(256) void k_dec(const float* __restrict__ zcre,
    const float* __restrict__ zim, const int* __restrict__ npredi,
    const float* __restrict__ w1, const float* __restrict__ b1,
    const float* __restrict__ w2, const float* __restrict__ b2,
    float* __restrict__ xr) {
    int m = blockIdx.x, b = blockIdx.y;
    int tid = threadIdx.x;
    size_t row = (size_t)b * NMAXX + m;
    if (m >= npredi[b]) {
        if (tid < DIMX) xr[row * DIMX + tid] = 0.0f;
        return;
    }
    __shared__ float zp[HIDX];
    __shared__ float a[DMID];
    {
        float t = (float)tid * (1.0f / 255.0f);
        float sv, cv;
        sincosf((t * (float)m) * 8.0f, &sv, &cv);
        zp[tid] = zcre[(size_t)b * HIDX + tid] * cv - zim[(size_t)b * HIDX + tid] * sv;
    }
    __syncthreads();
    if (tid < DMID) {
        float v = b1[tid];
#pragma unroll 4
        for (int k = 0; k < HIDX; k++) v += zp[k] * w1[k * DMID + tid];
        a[tid] = mishf(v);
    }
    __syncthreads();
    if (tid < DIMX) {
        float v = b2[tid];
#pragma unroll 4
        for (int k = 0; k < DMID; k++) v += a[k] * w2[k * DIMX + tid];
        xr[row * DIMX + tid] = v;
    }
}

extern "C" void kernel_launch(void* const* d_in, const int* in_sizes, int n_in,
                              void* d_out, int out_size, void* d_ws, size_t ws_size,
                              hipStream_t stream) {
    const float* x      = (const float*)d_in[0];
    const int*   batch  = (const int*)d_in[1];
    const float* rank_w = (const float*)d_in[2];
    const float* rank_b = (const float*)d_in[3];
    const float* vw1    = (const float*)d_in[4];
    const float* vb1    = (const float*)d_in[5];
    const float* vlg    = (const float*)d_in[6];
    const float* vlb    = (const float*)d_in[7];
    const float* vw2    = (const float*)d_in[8];
    const float* vb2    = (const float*)d_in[9];
    const float* cw     = (const float*)d_in[10];
    const float* cb     = (const float*)d_in[11];
    const float* sw1    = (const float*)d_in[12];
    const float* sb1    = (const float*)d_in[13];
    const float* slg    = (const float*)d_in[14];
    const float* slb    = (const float*)d_in[15];
    const float* sw2    = (const float*)d_in[16];
    const float* sb2    = (const float*)d_in[17];
    const float* dw1    = (const float*)d_in[18];
    const float* db1    = (const float*)d_in[19];
    const float* dw2    = (const float*)d_in[20];
    const float* db2    = (const float*)d_in[21];

    char* ws = (char*)d_ws;
    size_t off = 0;
    auto alloc = [&](size_t bytes) {
        void* p = ws + off;
        off += (bytes + 255) & ~(size_t)255;
        return p;
    };
    float* mag  = (float*)alloc((size_t)NTOTX * 4);
    float* zre  = (float*)alloc((size_t)NBX * HIDX * 4);
    float* zim  = (float*)alloc((size_t)NBX * HIDX * 4);
    float* zcre = (float*)alloc((size_t)NBX * HIDX * 4);
    int*   npi  = (int*)alloc((size_t)NBX * 4);
    float* h    = (float*)alloc((size_t)NTOTX * HIDX * 4);

    float* out_xr   = (float*)d_out;
    float* out_mask = out_xr + (size_t)NBX * NMAXX * DIMX;
    float* out_np   = out_mask + (size_t)NBX * NMAXX;

    hipLaunchKernelGGL(k_enc,  dim3(NTOTX / EROWS), dim3(1024), 0, stream,
                       x, rank_w, rank_b, vw1, vb1, vlg, vlb, vw2, vb2, h, mag);
    hipLaunchKernelGGL(k_z,    dim3(NBX), dim3(HIDX), 0, stream,
                       h, batch, mag, cw, cb, zre, zim);
    hipLaunchKernelGGL(k_size, dim3(NBX / 8), dim3(256), 0, stream,
                       zre, cw, cb, sw1, sb1, slg, slb, sw2, sb2,
                       zcre, out_mask, out_np, npi);
    hipLaunchKernelGGL(k_dec,  dim3(NMAXX, NBX), dim3(256), 0, stream,
                       zcre, zim, npi, dw1, db1, dw2, db2, out_xr);
    (void)in_sizes; (void)n_in; (void)out_size; (void)ws_size;
}